// Round 13
// baseline (11223.206 us; speedup 1.0000x reference)
//
#include <hip/hip_runtime.h>
#include <hip/hip_bf16.h>
#include <hip/hip_fp16.h>

typedef __attribute__((ext_vector_type(8))) _Float16 half8;
typedef __attribute__((ext_vector_type(4))) _Float16 half4v;
typedef __attribute__((ext_vector_type(4))) float f32x4;

#define T_LEN 2048
#define NCH 128
#define CHS 16
#define L2E 1.4426950408889634f

__device__ __forceinline__ float rcpf_(float x){ return __builtin_amdgcn_rcpf(x); }

__device__ __forceinline__ half4v pack4(float4 a){
  half4v r;
  r[0]=(_Float16)a.x; r[1]=(_Float16)a.y; r[2]=(_Float16)a.z; r[3]=(_Float16)a.w;
  return r;
}
__device__ __forceinline__ half8 pack8s(float4 a, float4 b, float s){
  half8 r;
  r[0]=(_Float16)(a.x*s); r[1]=(_Float16)(a.y*s); r[2]=(_Float16)(a.z*s); r[3]=(_Float16)(a.w*s);
  r[4]=(_Float16)(b.x*s); r[5]=(_Float16)(b.y*s); r[6]=(_Float16)(b.z*s); r[7]=(_Float16)(b.w*s);
  return r;
}

// gate pre-scales (PyTorch order i,f,g,o): exp(-i)=2^(-L*i), exp(2g)=2^(2L*g)
__device__ __constant__ float GSC[4] = { -L2E, -L2E, 2.f*L2E, -L2E };

// ---------------------------------------------------------------------------
// Kernel 1: gate table = scale * (emb @ Wih.T + bias), per direction.
// Layout: [dir][v][w(8)][hi(4)][g(4)][4] f32  (each (v,w,hi) = 64B contiguous)
__global__ __launch_bounds__(512) void k_table(const float* __restrict__ emb,
    const float* __restrict__ Wih_f, const float* __restrict__ b_f,
    const float* __restrict__ Wih_b, const float* __restrict__ b_b,
    float* __restrict__ table){
  const int dir = blockIdx.x & 1, vt = blockIdx.x >> 1;
  const float* Wih  = dir ? Wih_b : Wih_f;
  const float* bias = dir ? b_b  : b_f;
  const int w = threadIdx.x >> 6, l = threadIdx.x & 63;
  const int lA = l & 15, hi = l >> 4;

  half4v wf[4][8];
#pragma unroll
  for (int g = 0; g < 4; ++g)
#pragma unroll
    for (int kb = 0; kb < 8; ++kb){
      const size_t base = (size_t)(g*128 + 16*w + lA)*128 + kb*16 + 4*hi;
      wf[g][kb] = pack4(*reinterpret_cast<const float4*>(Wih + base));
    }
  const int v0 = vt*16;
  half4v bfr[8];
#pragma unroll
  for (int kb = 0; kb < 8; ++kb){
    const size_t base = (size_t)(v0 + lA)*128 + kb*16 + 4*hi;
    bfr[kb] = pack4(*reinterpret_cast<const float4*>(emb + base));
  }
  f32x4 acc[4];
#pragma unroll
  for (int g = 0; g < 4; ++g)
    acc[g] = *reinterpret_cast<const f32x4*>(bias + g*128 + 16*w + 4*hi);
#pragma unroll
  for (int kb = 0; kb < 8; ++kb)
#pragma unroll
    for (int g = 0; g < 4; ++g)
      acc[g] = __builtin_amdgcn_mfma_f32_16x16x16f16(wf[g][kb], bfr[kb], acc[g], 0, 0, 0);
  float* outp = table + ((((size_t)dir*4096 + v0 + lA)*8 + w)*4 + hi)*16;
#pragma unroll
  for (int g = 0; g < 4; ++g){
    f32x4 v = acc[g]*GSC[g];
    *reinterpret_cast<f32x4*>(outp + g*4) = v;
  }
}

// ---------------------------------------------------------------------------
// LSTM epilogue on pre-scaled gates: ei=-L*i, ef=-L*f, eg=2L*g, eo=-L*o.
__device__ __forceinline__ void epi_step(float ei, float ef, float eg, float eo,
                                         float& c, float& h){
  float Ae = exp2f(ei);                       // e^{-i}
  float Be = exp2f(eg);                       // e^{2g}
  float st = (Be - 1.f) * rcpf_((1.f + Ae)*(Be + 1.f));   // sig(i)*tanh(g)
  float Fe = exp2f(ef);                       // e^{-f}
  float cn = rcpf_(1.f + Fe)*c + st;
  c = cn;
  float Oe = exp2f(eo);                       // e^{-o}
  float Ce = exp2f(2.f*L2E*cn);               // e^{2c}
  h = (Ce - 1.f) * rcpf_((1.f + Oe)*(Ce + 1.f));          // sig(o)*tanh(c)
}

#define MFMA32 __builtin_amdgcn_mfma_f32_16x16x32_f16

// One chain-substep (per wave, 1 unit-block): ds_read h-frag, 16 MFMA (table
// value as C), refill table prefetch buffer, epilogue, ds_write h' + hcat.
#define SUBSTEP(HSRC, LDSW, TB, IDXV, TX) do{                                 \
  half8 ah0 = *reinterpret_cast<const half8*>(&HSRC[0][l][0]);                \
  half8 ah1 = *reinterpret_cast<const half8*>(&HSRC[1][l][0]);                \
  half8 ah2 = *reinterpret_cast<const half8*>(&HSRC[2][l][0]);                \
  half8 ah3 = *reinterpret_cast<const half8*>(&HSRC[3][l][0]);                \
  f32x4 a0 = MFMA32(whh[0][0], ah0, TB[0], 0, 0, 0);                          \
  f32x4 a1 = MFMA32(whh[1][0], ah0, TB[1], 0, 0, 0);                          \
  f32x4 a2 = MFMA32(whh[2][0], ah0, TB[2], 0, 0, 0);                          \
  f32x4 a3 = MFMA32(whh[3][0], ah0, TB[3], 0, 0, 0);                          \
  { const float* _pf = tblD + (size_t)(IDXV)*512 + seg;                       \
    TB[0] = *reinterpret_cast<const f32x4*>(_pf);                             \
    TB[1] = *reinterpret_cast<const f32x4*>(_pf + 4);                         \
    TB[2] = *reinterpret_cast<const f32x4*>(_pf + 8);                         \
    TB[3] = *reinterpret_cast<const f32x4*>(_pf + 12); }                      \
  a0 = MFMA32(whh[0][1], ah1, a0, 0, 0, 0);                                   \
  a1 = MFMA32(whh[1][1], ah1, a1, 0, 0, 0);                                   \
  a2 = MFMA32(whh[2][1], ah1, a2, 0, 0, 0);                                   \
  a3 = MFMA32(whh[3][1], ah1, a3, 0, 0, 0);                                   \
  a0 = MFMA32(whh[0][2], ah2, a0, 0, 0, 0);                                   \
  a1 = MFMA32(whh[1][2], ah2, a1, 0, 0, 0);                                   \
  a2 = MFMA32(whh[2][2], ah2, a2, 0, 0, 0);                                   \
  a3 = MFMA32(whh[3][2], ah2, a3, 0, 0, 0);                                   \
  a0 = MFMA32(whh[0][3], ah3, a0, 0, 0, 0);                                   \
  a1 = MFMA32(whh[1][3], ah3, a1, 0, 0, 0);                                   \
  a2 = MFMA32(whh[2][3], ah3, a2, 0, 0, 0);                                   \
  a3 = MFMA32(whh[3][3], ah3, a3, 0, 0, 0);                                   \
  float hv0, hv1, hv2, hv3;                                                   \
  epi_step(a0[0], a1[0], a2[0], a3[0], cc0, hv0);                             \
  epi_step(a0[1], a1[1], a2[1], a3[1], cc1, hv1);                             \
  epi_step(a0[2], a1[2], a2[2], a3[2], cc2, hv2);                             \
  epi_step(a0[3], a1[3], a2[3], a3[3], cc3, hv3);                             \
  half4v hp;                                                                  \
  hp[0]=(_Float16)hv0; hp[1]=(_Float16)hv1; hp[2]=(_Float16)hv2; hp[3]=(_Float16)hv3; \
  *reinterpret_cast<half4v*>(LDSW) = hp;                                      \
  *reinterpret_cast<half4v*>(hg + (size_t)(TX)*16384) = hp;                   \
}while(0)

// ---------------------------------------------------------------------------
// Kernel 2: persistent BiLSTM. grid = 4 blocks (batch-group), 1024 threads =
// 16 waves = 2 chains (waves 0-7: forward, 8-15: backward). Per-chain LDS
// flag sync so the two chains free-run in anti-phase on the shared SIMDs.
// Sync cost fix vs R8: flag post by LANE 0 ONLY (8 ds_adds/step, not 512);
// poll loop throttled with s_sleep (poll read is same-address broadcast).
__global__ __launch_bounds__(1024, 1) void k_lstm(
    const float* __restrict__ Whh_f, const float* __restrict__ Whh_b,
    const int* __restrict__ x, const float* __restrict__ table,
    _Float16* __restrict__ hcat){
  const int bg = blockIdx.x;            // batch group 0..3
  const int w  = threadIdx.x >> 6;      // 0..15
  const int ch = w >> 3;                // 0 fwd, 1 bwd
  const int wl = w & 7;                 // unit-block within chain
  const int l  = threadIdx.x & 63;
  const int lA = l & 15;
  const int hi = l >> 4;
  const int d  = ch;
  const float* Whh  = d ? Whh_b : Whh_f;
  const float* tblD = table + (size_t)d*4096*512;

  // K=32 A-fragments (two K=16 canonical halves per half8), gate-pre-scaled
  half8 whh[4][4];
#pragma unroll
  for (int g = 0; g < 4; ++g)
#pragma unroll
    for (int q = 0; q < 4; ++q){
      const size_t base = (size_t)(g*128 + 16*wl + lA)*128 + q*32 + 4*hi;
      whh[g][q] = pack8s(*reinterpret_cast<const float4*>(Whh + base),
                         *reinterpret_cast<const float4*>(Whh + base + 16), GSC[g]);
    }

  __shared__ __align__(16) _Float16 hbuf[2][2][4][64][8]; // [chain][parity][q][lane][8]
  __shared__ int cnt[2][2];                               // [chain][parity]
  reinterpret_cast<int4*>(&hbuf[0][0][0][0][0])[threadIdx.x] = make_int4(0,0,0,0);
  if (threadIdx.x < 4) cnt[threadIdx.x >> 1][threadIdx.x & 1] = ((threadIdx.x & 1) == 0) ? 8 : 0;
  __syncthreads();

  volatile int* vc = &cnt[ch][0];

  const int b = bg*16 + lA;
  const int* xrow = x + (size_t)b*T_LEN;
  _Float16* hg = hcat + (size_t)b*256 + d*128 + 16*wl + 4*hi;
  _Float16* ldsw0 = &hbuf[ch][0][wl>>1][l][4*(wl&1)];
  _Float16* ldsw1 = &hbuf[ch][1][wl>>1][l][4*(wl&1)];
  const int seg = (wl*4 + hi)*16;       // 64B segment within a table row

  // prologue: depth-2 prefetch (even/odd buffers)
  f32x4 tbE[4], tbO[4];
  int idxE, idxO;
  {
    const int xiE = d ? (T_LEN-1) : 0;
    const int xiO = d ? (T_LEN-2) : 1;
    const float* pE = tblD + (size_t)xrow[xiE]*512 + seg;
    const float* pO = tblD + (size_t)xrow[xiO]*512 + seg;
#pragma unroll
    for (int g = 0; g < 4; ++g) tbE[g] = *reinterpret_cast<const f32x4*>(pE + g*4);
#pragma unroll
    for (int g = 0; g < 4; ++g) tbO[g] = *reinterpret_cast<const f32x4*>(pO + g*4);
    idxE = xrow[d ? (T_LEN-3) : 2];
    idxO = xrow[d ? (T_LEN-4) : 3];
  }
  float cc0=0.f, cc1=0.f, cc2=0.f, cc3=0.f;
  int expv = 8;

  for (int tt = 0; tt < T_LEN; tt += 2){
    // ===== even step t=tt : read parity 0, write parity 1 =====
    {
      while (vc[0] < expv) { __builtin_amdgcn_s_sleep(1); }
      asm volatile("" ::: "memory");
      __builtin_amdgcn_sched_barrier(0);
      const int tx = d ? (T_LEN-1-tt) : tt;
      SUBSTEP(hbuf[ch][0], ldsw1, tbE, idxE, tx);
      const int tn = (tt+4 < T_LEN) ? tt+4 : T_LEN-1;
      idxE = xrow[d ? (T_LEN-1-tn) : tn];
      asm volatile("s_waitcnt lgkmcnt(0)" ::: "memory");
      __builtin_amdgcn_sched_barrier(0);
      if (l == 0) atomicAdd(&cnt[ch][1], 1);
    }
    // ===== odd step t=tt+1 : read parity 1, write parity 0 =====
    {
      while (vc[1] < expv) { __builtin_amdgcn_s_sleep(1); }
      asm volatile("" ::: "memory");
      __builtin_amdgcn_sched_barrier(0);
      const int tx = d ? (T_LEN-2-tt) : tt+1;
      SUBSTEP(hbuf[ch][1], ldsw0, tbO, idxO, tx);
      const int tn = (tt+5 < T_LEN) ? tt+5 : T_LEN-1;
      idxO = xrow[d ? (T_LEN-1-tn) : tn];
      asm volatile("s_waitcnt lgkmcnt(0)" ::: "memory");
      __builtin_amdgcn_sched_barrier(0);
      if (l == 0) atomicAdd(&cnt[ch][0], 1);
    }
    expv += 8;
  }
}

// ---------------------------------------------------------------------------
// Kernel 3: CRF chunk transition matrices (log-semiring chain product).
__global__ __launch_bounds__(256) void k_crfchunk(const _Float16* __restrict__ hcat,
    const float* __restrict__ fc_w, const float* __restrict__ fc_b,
    const float* __restrict__ trans, float* __restrict__ chunkP){
  const int wv = threadIdx.x >> 6;
  const int l  = threadIdx.x & 63;
  const int task = blockIdx.x*4 + wv;   // k*64 + b
  const int k = task >> 6;
  const int b = task & 63;
  const int i = l >> 3, jc = l & 7;
  float trC[8];
#pragma unroll
  for (int kk = 0; kk < 8; ++kk) trC[kk] = trans[kk*8 + jc];
  const float tii = trans[l];
  float wreg[32];
#pragma unroll
  for (int q = 0; q < 32; ++q) wreg[q] = fc_w[jc*256 + i*32 + q];
  const float fcb = fc_b[jc];
  const int tstart = 1 + k*CHS;
  const int len = (CHS < T_LEN - tstart) ? CHS : (T_LEN - tstart);
  float P = 0.f;
  for (int s = 0; s < len; ++s){
    const int t = tstart + s;
    const _Float16* hp = hcat + ((size_t)t*64 + b)*256 + i*32;
    float dot = 0.f;
#pragma unroll
    for (int q8 = 0; q8 < 4; ++q8){
      half8 hv = *reinterpret_cast<const half8*>(hp + q8*8);
#pragma unroll
      for (int j = 0; j < 8; ++j) dot += (float)hv[j] * wreg[q8*8 + j];
    }
    dot += __shfl_xor(dot, 8);
    dot += __shfl_xor(dot, 16);
    dot += __shfl_xor(dot, 32);
    const float em = fcb + dot;
    if (s == 0){
      P = tii + em;
    } else {
      float v[8];
#pragma unroll
      for (int kk = 0; kk < 8; ++kk) v[kk] = __shfl(P, (l & 56) | kk) + trC[kk];
      float m = v[0];
#pragma unroll
      for (int kk = 1; kk < 8; ++kk) m = fmaxf(m, v[kk]);
      float ss = 0.f;
#pragma unroll
      for (int kk = 0; kk < 8; ++kk) ss += __expf(v[kk] - m);
      P = m + __logf(ss) + em;
    }
  }
  chunkP[(size_t)task*64 + l] = P;
}

// ---------------------------------------------------------------------------
// Kernel 4: fold alpha0 through 128 chunk matrices, LSE with end.
__global__ __launch_bounds__(512) void k_crffinal(const _Float16* __restrict__ hcat,
    const float* __restrict__ fc_w, const float* __restrict__ fc_b,
    const float* __restrict__ trans, const float* __restrict__ startv,
    const float* __restrict__ endv, const float* __restrict__ chunkP,
    float* __restrict__ out){
  const int tid = threadIdx.x;
  const int b = tid >> 3, jc = tid & 7;
  const int l = tid & 63;
  float em = fc_b[jc];
  const _Float16* hp = hcat + (size_t)b*256;   // t = 0
  const float* wr = fc_w + jc*256;
#pragma unroll
  for (int q = 0; q < 32; ++q){
    half8 hv = *reinterpret_cast<const half8*>(hp + q*8);
#pragma unroll
    for (int j = 0; j < 8; ++j) em += (float)hv[j] * wr[q*8 + j];
  }
  float alpha = startv[jc] + em;
  for (int k = 0; k < NCH; ++k){
    const float* pk = chunkP + ((size_t)k*64 + b)*64;
    float v[8];
#pragma unroll
    for (int kk = 0; kk < 8; ++kk) v[kk] = __shfl(alpha, (l & 56) | kk) + pk[kk*8 + jc];
    float m = v[0];
#pragma unroll
    for (int kk = 1; kk < 8; ++kk) m = fmaxf(m, v[kk]);
    float ss = 0.f;
#pragma unroll
    for (int kk = 0; kk < 8; ++kk) ss += __expf(v[kk] - m);
    alpha = m + __logf(ss);
  }
  float vf = alpha + endv[jc];
  float m = vf;
  m = fmaxf(m, __shfl_xor(m, 1));
  m = fmaxf(m, __shfl_xor(m, 2));
  m = fmaxf(m, __shfl_xor(m, 4));
  float e = __expf(vf - m);
  e += __shfl_xor(e, 1);
  e += __shfl_xor(e, 2);
  e += __shfl_xor(e, 4);
  if (jc == 0) out[b] = m + __logf(e);
}

// ---------------------------------------------------------------------------
extern "C" void kernel_launch(void* const* d_in, const int* in_sizes, int n_in,
                              void* d_out, int out_size, void* d_ws, size_t ws_size,
                              hipStream_t stream){
  const int*   x     = (const int*)d_in[0];
  const float* emb   = (const float*)d_in[1];
  const float* Wih_f = (const float*)d_in[2];
  const float* Whh_f = (const float*)d_in[3];
  const float* b_f   = (const float*)d_in[4];
  const float* Wih_b = (const float*)d_in[5];
  const float* Whh_b = (const float*)d_in[6];
  const float* b_b   = (const float*)d_in[7];
  const float* fc_w  = (const float*)d_in[8];
  const float* fc_b  = (const float*)d_in[9];
  const float* trans = (const float*)d_in[10];
  const float* startp= (const float*)d_in[11];
  const float* endp  = (const float*)d_in[12];
  float* out = (float*)d_out;

  const size_t off_tbl  = 0;
  const size_t off_hcat = 16777216;               // 2*4096*512*4
  const size_t off_chk  = 16777216 + 67108864;    // + 2048*64*256*2
  const size_t need     = off_chk + 2097152;      // + 128*64*64*4
  if (ws_size < need){
    (void)hipMemsetAsync(d_out, 0, 64*sizeof(float), stream);
    return;
  }
  float* table  = (float*)((char*)d_ws + off_tbl);
  _Float16* hcat = (_Float16*)((char*)d_ws + off_hcat);
  float* chunkP  = (float*)((char*)d_ws + off_chk);

  k_table<<<512, 512, 0, stream>>>(emb, Wih_f, b_f, Wih_b, b_b, table);
  k_lstm<<<4, 1024, 0, stream>>>(Whh_f, Whh_b, x, table, hcat);
  k_crfchunk<<<2048, 256, 0, stream>>>(hcat, fc_w, fc_b, trans, chunkP);
  k_crffinal<<<1, 512, 0, stream>>>(hcat, fc_w, fc_b, trans, startp, endp, chunkP, out);
}

// Round 14
// 2598.076 us; speedup vs baseline: 4.3198x; 4.3198x over previous
//
#include <hip/hip_runtime.h>
#include <hip/hip_bf16.h>
#include <hip/hip_fp16.h>

typedef __attribute__((ext_vector_type(8))) _Float16 half8;
typedef __attribute__((ext_vector_type(4))) _Float16 half4v;
typedef __attribute__((ext_vector_type(4))) float f32x4;

#define T_LEN 2048
#define NCH 128
#define CHS 16

__device__ __forceinline__ float rcpf_(float x){ return __builtin_amdgcn_rcpf(x); }

__device__ __forceinline__ half4v pack4(float4 a){
  half4v r;
  r[0]=(_Float16)a.x; r[1]=(_Float16)a.y; r[2]=(_Float16)a.z; r[3]=(_Float16)a.w;
  return r;
}
__device__ __forceinline__ half8 pack8(float4 a, float4 b){
  half8 r;
  r[0]=(_Float16)a.x; r[1]=(_Float16)a.y; r[2]=(_Float16)a.z; r[3]=(_Float16)a.w;
  r[4]=(_Float16)b.x; r[5]=(_Float16)b.y; r[6]=(_Float16)b.z; r[7]=(_Float16)b.w;
  return r;
}

// ---------------------------------------------------------------------------
// Kernel 1: gate table = emb @ Wih.T + bias, per direction.
// Layout: [dir][v][w(8)][hi(4)][g(4)][4] f32  (each (v,w,hi) = 64B contiguous)
// mfma 16x16x16f16 canonical: A/B lane l: m(n)=l&15, k=4*(l>>4)+j.
// C/D: col=l&15, row=4*(l>>4)+reg.  (16x16x32: two K=16 halves, j<4 | j>=4)
__global__ __launch_bounds__(512) void k_table(const float* __restrict__ emb,
    const float* __restrict__ Wih_f, const float* __restrict__ b_f,
    const float* __restrict__ Wih_b, const float* __restrict__ b_b,
    float* __restrict__ table){
  const int dir = blockIdx.x & 1, vt = blockIdx.x >> 1;
  const float* Wih  = dir ? Wih_b : Wih_f;
  const float* bias = dir ? b_b  : b_f;
  const int w = threadIdx.x >> 6, l = threadIdx.x & 63;
  const int lA = l & 15, hi = l >> 4;

  half4v wf[4][8];
#pragma unroll
  for (int g = 0; g < 4; ++g)
#pragma unroll
    for (int kb = 0; kb < 8; ++kb){
      const size_t base = (size_t)(g*128 + 16*w + lA)*128 + kb*16 + 4*hi;
      wf[g][kb] = pack4(*reinterpret_cast<const float4*>(Wih + base));
    }
  const int v0 = vt*16;
  half4v bfr[8];
#pragma unroll
  for (int kb = 0; kb < 8; ++kb){
    const size_t base = (size_t)(v0 + lA)*128 + kb*16 + 4*hi;
    bfr[kb] = pack4(*reinterpret_cast<const float4*>(emb + base));
  }
  f32x4 acc[4];
#pragma unroll
  for (int g = 0; g < 4; ++g)
    acc[g] = *reinterpret_cast<const f32x4*>(bias + g*128 + 16*w + 4*hi);
#pragma unroll
  for (int kb = 0; kb < 8; ++kb)
#pragma unroll
    for (int g = 0; g < 4; ++g)
      acc[g] = __builtin_amdgcn_mfma_f32_16x16x16f16(wf[g][kb], bfr[kb], acc[g], 0, 0, 0);
  float* outp = table + ((((size_t)dir*4096 + v0 + lA)*8 + w)*4 + hi)*16;
#pragma unroll
  for (int g = 0; g < 4; ++g)
    *reinterpret_cast<f32x4*>(outp + g*4) = acc[g];
}

// ---------------------------------------------------------------------------
// LSTM epilogue: c' = sig(f)*c + sig(i)*tanh(g); h = sig(o)*tanh(c')
__device__ __forceinline__ void epi_step(float iv, float fv, float gv, float ov,
                                         float& c, float& h){
  float Ae = __expf(-iv);
  float Be = __expf(2.f*gv);
  float st = (Be - 1.f) * rcpf_((1.f + Ae)*(Be + 1.f));
  float Fe = __expf(-fv);
  float cn = rcpf_(1.f + Fe)*c + st;
  c = cn;
  float Oe = __expf(-ov);
  float Ce = __expf(2.f*cn);
  h = (Ce - 1.f) * rcpf_((1.f + Oe)*(Ce + 1.f));
}

// ---------------------------------------------------------------------------
// Kernel 2: persistent BiLSTM, 16x16x32 MFMA, unroll-2, depth-2 prefetch.
// grid = 8 blocks (dir*4 + chain), 512 threads = 8 waves.
// Wave w: units [16w,16w+16) all gates. hbuf[buf][q][lane][8]: half8 B-frag
// for K-block pair q (k in [32q,32q+32)) read as one ds_read_b128.
__global__ __launch_bounds__(512, 2) void k_lstm(
    const float* __restrict__ Whh_f, const float* __restrict__ Whh_b,
    const int* __restrict__ x, const float* __restrict__ table,
    _Float16* __restrict__ hcat){
  const int dir = blockIdx.x >> 2;
  const int chain = blockIdx.x & 3;
  const float* Whh = dir ? Whh_b : Whh_f;
  const float* tbl = table + (size_t)dir*4096*512;
  const int w  = threadIdx.x >> 6;
  const int l  = threadIdx.x & 63;
  const int lA = l & 15;
  const int hi = l >> 4;

  // K=32 fragments: two K=16 canonical halves packed per half8
  half8 whh[4][4];
#pragma unroll
  for (int g = 0; g < 4; ++g)
#pragma unroll
    for (int q = 0; q < 4; ++q){
      const size_t base = (size_t)(g*128 + 16*w + lA)*128 + q*32 + 4*hi;
      whh[g][q] = pack8(*reinterpret_cast<const float4*>(Whh + base),
                        *reinterpret_cast<const float4*>(Whh + base + 16));
    }

  __shared__ __align__(16) _Float16 hbuf[2][4][64][8];
  reinterpret_cast<int4*>(&hbuf[0][0][0][0])[threadIdx.x] = make_int4(0,0,0,0);
  __syncthreads();

  const int b = chain*16 + lA;
  const int* xrow = x + (size_t)b*T_LEN;
  _Float16* hgbase = hcat + (size_t)b*256 + dir*128 + 16*w + 4*hi;
  // lane's h' (units 16w+4hi..+3) = K-pair q=w>>1, half (w&1)
  _Float16* ldsw0 = &hbuf[0][w>>1][l][4*(w&1)];
  _Float16* ldsw1 = &hbuf[1][w>>1][l][4*(w&1)];
  const int seg = (w*4 + hi)*16;          // lane's 64B segment within a row

  // prologue: depth-2 prefetch
  f32x4 tbA[4], tbB[4];
  int idxA2, idxB2;
  {
    const int i0 = xrow[dir ? 2047 : 0];
    const int i1 = xrow[dir ? 2046 : 1];
    const float* pA = tbl + (size_t)i0*512 + seg;
    const float* pB = tbl + (size_t)i1*512 + seg;
#pragma unroll
    for (int g = 0; g < 4; ++g) tbA[g] = *reinterpret_cast<const f32x4*>(pA + g*4);
#pragma unroll
    for (int g = 0; g < 4; ++g) tbB[g] = *reinterpret_cast<const f32x4*>(pB + g*4);
    idxA2 = xrow[dir ? 2045 : 2];
    idxB2 = xrow[dir ? 2044 : 3];
  }
  float cc0=0.f, cc1=0.f, cc2=0.f, cc3=0.f;

  for (int tt = 0; tt < T_LEN; tt += 2){
    // ================= even step t=tt : read hbuf[0], write hbuf[1] ========
    {
      half8 ah[4];
#pragma unroll
      for (int q = 0; q < 4; ++q)
        ah[q] = *reinterpret_cast<const half8*>(&hbuf[0][q][l][0]);
      f32x4 acc[4];
#pragma unroll
      for (int g = 0; g < 4; ++g)
        acc[g] = __builtin_amdgcn_mfma_f32_16x16x32_f16(whh[g][0], ah[0], tbA[g], 0, 0, 0);
      { // reissue tbA <- gates(t+2)
        const float* pA = tbl + (size_t)idxA2*512 + seg;
#pragma unroll
        for (int g = 0; g < 4; ++g) tbA[g] = *reinterpret_cast<const f32x4*>(pA + g*4);
        const int tn = (tt+4 < T_LEN) ? tt+4 : T_LEN-1;
        idxA2 = xrow[dir ? (T_LEN-1-tn) : tn];
      }
#pragma unroll
      for (int q = 1; q < 4; ++q)
#pragma unroll
        for (int g = 0; g < 4; ++g)
          acc[g] = __builtin_amdgcn_mfma_f32_16x16x32_f16(whh[g][q], ah[q], acc[g], 0, 0, 0);

      float hv0, hv1, hv2, hv3;
      epi_step(acc[0][0], acc[1][0], acc[2][0], acc[3][0], cc0, hv0);
      epi_step(acc[0][1], acc[1][1], acc[2][1], acc[3][1], cc1, hv1);
      epi_step(acc[0][2], acc[1][2], acc[2][2], acc[3][2], cc2, hv2);
      epi_step(acc[0][3], acc[1][3], acc[2][3], acc[3][3], cc3, hv3);
      half4v hp;
      hp[0]=(_Float16)hv0; hp[1]=(_Float16)hv1; hp[2]=(_Float16)hv2; hp[3]=(_Float16)hv3;
      *reinterpret_cast<half4v*>(ldsw1) = hp;
      const int tx = dir ? (T_LEN-1-tt) : tt;
      *reinterpret_cast<half4v*>(hgbase + (size_t)tx*16384) = hp;
      asm volatile("s_waitcnt lgkmcnt(0)" ::: "memory");
      __builtin_amdgcn_sched_barrier(0);
      __builtin_amdgcn_s_barrier();
      __builtin_amdgcn_sched_barrier(0);
    }
    // ================= odd step t=tt+1 : read hbuf[1], write hbuf[0] =======
    {
      half8 ah[4];
#pragma unroll
      for (int q = 0; q < 4; ++q)
        ah[q] = *reinterpret_cast<const half8*>(&hbuf[1][q][l][0]);
      f32x4 acc[4];
#pragma unroll
      for (int g = 0; g < 4; ++g)
        acc[g] = __builtin_amdgcn_mfma_f32_16x16x32_f16(whh[g][0], ah[0], tbB[g], 0, 0, 0);
      { // reissue tbB <- gates(t+3)
        const float* pB = tbl + (size_t)idxB2*512 + seg;
#pragma unroll
        for (int g = 0; g < 4; ++g) tbB[g] = *reinterpret_cast<const f32x4*>(pB + g*4);
        const int tn = (tt+5 < T_LEN) ? tt+5 : T_LEN-1;
        idxB2 = xrow[dir ? (T_LEN-1-tn) : tn];
      }
#pragma unroll
      for (int q = 1; q < 4; ++q)
#pragma unroll
        for (int g = 0; g < 4; ++g)
          acc[g] = __builtin_amdgcn_mfma_f32_16x16x32_f16(whh[g][q], ah[q], acc[g], 0, 0, 0);

      float hv0, hv1, hv2, hv3;
      epi_step(acc[0][0], acc[1][0], acc[2][0], acc[3][0], cc0, hv0);
      epi_step(acc[0][1], acc[1][1], acc[2][1], acc[3][1], cc1, hv1);
      epi_step(acc[0][2], acc[1][2], acc[2][2], acc[3][2], cc2, hv2);
      epi_step(acc[0][3], acc[1][3], acc[2][3], acc[3][3], cc3, hv3);
      half4v hp;
      hp[0]=(_Float16)hv0; hp[1]=(_Float16)hv1; hp[2]=(_Float16)hv2; hp[3]=(_Float16)hv3;
      *reinterpret_cast<half4v*>(ldsw0) = hp;
      const int tx = dir ? (T_LEN-2-tt) : tt+1;
      *reinterpret_cast<half4v*>(hgbase + (size_t)tx*16384) = hp;
      asm volatile("s_waitcnt lgkmcnt(0)" ::: "memory");
      __builtin_amdgcn_sched_barrier(0);
      __builtin_amdgcn_s_barrier();
      __builtin_amdgcn_sched_barrier(0);
    }
  }
}

// ---------------------------------------------------------------------------
// Kernel 3: CRF chunk transition matrices (log-semiring chain product).
__global__ __launch_bounds__(256) void k_crfchunk(const _Float16* __restrict__ hcat,
    const float* __restrict__ fc_w, const float* __restrict__ fc_b,
    const float* __restrict__ trans, float* __restrict__ chunkP){
  const int wv = threadIdx.x >> 6;
  const int l  = threadIdx.x & 63;
  const int task = blockIdx.x*4 + wv;   // k*64 + b
  const int k = task >> 6;
  const int b = task & 63;
  const int i = l >> 3, jc = l & 7;
  float trC[8];
#pragma unroll
  for (int kk = 0; kk < 8; ++kk) trC[kk] = trans[kk*8 + jc];
  const float tii = trans[l];
  float wreg[32];
#pragma unroll
  for (int q = 0; q < 32; ++q) wreg[q] = fc_w[jc*256 + i*32 + q];
  const float fcb = fc_b[jc];
  const int tstart = 1 + k*CHS;
  const int len = (CHS < T_LEN - tstart) ? CHS : (T_LEN - tstart);
  float P = 0.f;
  for (int s = 0; s < len; ++s){
    const int t = tstart + s;
    const _Float16* hp = hcat + ((size_t)t*64 + b)*256 + i*32;
    float dot = 0.f;
#pragma unroll
    for (int q8 = 0; q8 < 4; ++q8){
      half8 hv = *reinterpret_cast<const half8*>(hp + q8*8);
#pragma unroll
      for (int j = 0; j < 8; ++j) dot += (float)hv[j] * wreg[q8*8 + j];
    }
    dot += __shfl_xor(dot, 8);
    dot += __shfl_xor(dot, 16);
    dot += __shfl_xor(dot, 32);
    const float em = fcb + dot;
    if (s == 0){
      P = tii + em;
    } else {
      float v[8];
#pragma unroll
      for (int kk = 0; kk < 8; ++kk) v[kk] = __shfl(P, (l & 56) | kk) + trC[kk];
      float m = v[0];
#pragma unroll
      for (int kk = 1; kk < 8; ++kk) m = fmaxf(m, v[kk]);
      float ss = 0.f;
#pragma unroll
      for (int kk = 0; kk < 8; ++kk) ss += __expf(v[kk] - m);
      P = m + __logf(ss) + em;
    }
  }
  chunkP[(size_t)task*64 + l] = P;
}

// ---------------------------------------------------------------------------
// Kernel 4: fold alpha0 through 128 chunk matrices, LSE with end.
__global__ __launch_bounds__(512) void k_crffinal(const _Float16* __restrict__ hcat,
    const float* __restrict__ fc_w, const float* __restrict__ fc_b,
    const float* __restrict__ trans, const float* __restrict__ startv,
    const float* __restrict__ endv, const float* __restrict__ chunkP,
    float* __restrict__ out){
  const int tid = threadIdx.x;
  const int b = tid >> 3, jc = tid & 7;
  const int l = tid & 63;
  float em = fc_b[jc];
  const _Float16* hp = hcat + (size_t)b*256;   // t = 0
  const float* wr = fc_w + jc*256;
#pragma unroll
  for (int q = 0; q < 32; ++q){
    half8 hv = *reinterpret_cast<const half8*>(hp + q*8);
#pragma unroll
    for (int j = 0; j < 8; ++j) em += (float)hv[j] * wr[q*8 + j];
  }
  float alpha = startv[jc] + em;
  for (int k = 0; k < NCH; ++k){
    const float* pk = chunkP + ((size_t)k*64 + b)*64;
    float v[8];
#pragma unroll
    for (int kk = 0; kk < 8; ++kk) v[kk] = __shfl(alpha, (l & 56) | kk) + pk[kk*8 + jc];
    float m = v[0];
#pragma unroll
    for (int kk = 1; kk < 8; ++kk) m = fmaxf(m, v[kk]);
    float ss = 0.f;
#pragma unroll
    for (int kk = 0; kk < 8; ++kk) ss += __expf(v[kk] - m);
    alpha = m + __logf(ss);
  }
  float vf = alpha + endv[jc];
  float m = vf;
  m = fmaxf(m, __shfl_xor(m, 1));
  m = fmaxf(m, __shfl_xor(m, 2));
  m = fmaxf(m, __shfl_xor(m, 4));
  float e = __expf(vf - m);
  e += __shfl_xor(e, 1);
  e += __shfl_xor(e, 2);
  e += __shfl_xor(e, 4);
  if (jc == 0) out[b] = m + __logf(e);
}

// ---------------------------------------------------------------------------
extern "C" void kernel_launch(void* const* d_in, const int* in_sizes, int n_in,
                              void* d_out, int out_size, void* d_ws, size_t ws_size,
                              hipStream_t stream){
  const int*   x     = (const int*)d_in[0];
  const float* emb   = (const float*)d_in[1];
  const float* Wih_f = (const float*)d_in[2];
  const float* Whh_f = (const float*)d_in[3];
  const float* b_f   = (const float*)d_in[4];
  const float* Wih_b = (const float*)d_in[5];
  const float* Whh_b = (const float*)d_in[6];
  const float* b_b   = (const float*)d_in[7];
  const float* fc_w  = (const float*)d_in[8];
  const float* fc_b  = (const float*)d_in[9];
  const float* trans = (const float*)d_in[10];
  const float* startp= (const float*)d_in[11];
  const float* endp  = (const float*)d_in[12];
  float* out = (float*)d_out;

  const size_t off_tbl  = 0;
  const size_t off_hcat = 16777216;               // 2*4096*512*4
  const size_t off_chk  = 16777216 + 67108864;    // + 2048*64*256*2
  const size_t need     = off_chk + 2097152;      // + 128*64*64*4
  if (ws_size < need){
    (void)hipMemsetAsync(d_out, 0, 64*sizeof(float), stream);
    return;
  }
  float* table  = (float*)((char*)d_ws + off_tbl);
  _Float16* hcat = (_Float16*)((char*)d_ws + off_hcat);
  float* chunkP  = (float*)((char*)d_ws + off_chk);

  k_table<<<512, 512, 0, stream>>>(emb, Wih_f, b_f, Wih_b, b_b, table);
  k_lstm<<<8, 512, 0, stream>>>(Whh_f, Whh_b, x, table, hcat);
  k_crfchunk<<<2048, 256, 0, stream>>>(hcat, fc_w, fc_b, trans, chunkP);
  k_crffinal<<<1, 512, 0, stream>>>(hcat, fc_w, fc_b, trans, startp, endp, chunkP, out);
}